// Round 5
// baseline (185.653 us; speedup 1.0000x reference)
//
#include <hip/hip_runtime.h>
#include <math.h>

#define TOPK 13
#define PI_F 3.14159265358979323846f
#define K1_THREADS 512
#define K1_WAVES (K1_THREADS / 64)

typedef unsigned int u32;
typedef unsigned long long u64;

// monotone float -> uint mapping matching XLA total order
__device__ __forceinline__ u32 ford(float f) {
    u32 u = __float_as_uint(f);
    return (u & 0x80000000u) ? ~u : (u | 0x80000000u);
}
__device__ __forceinline__ float funord(u32 o) {
    u32 u = (o & 0x80000000u) ? (o & 0x7FFFFFFFu) : ~o;
    return __uint_as_float(u);
}

__device__ __forceinline__ float iou_fn(float4 g, float4 p) {
    float ltx = fmaxf(g.x, p.x), lty = fmaxf(g.y, p.y);
    float rbx = fminf(g.z, p.z), rby = fminf(g.w, p.w);
    float inter = fmaxf(rbx - ltx, 0.0f) * fmaxf(rby - lty, 0.0f);
    float a1 = fmaxf(g.z - g.x, 0.0f) * fmaxf(g.w - g.y, 0.0f);
    float a2 = fmaxf(p.z - p.x, 0.0f) * fmaxf(p.w - p.y, 0.0f);
    return inter / (((a1 + a2) - inter) + 1e-9f);
}

struct RowParams { float av, bar, offc, mx, mn; };

__device__ __forceinline__ RowParams row_params(float4 g) {
    float w = g.z - g.x, h = g.w - g.y;
    float ar = w / (h + 1e-5f);
    float ia = 1.0f / ar;
    RowParams rp;
    rp.av = ia / (2.0f - ia);
    rp.bar = 2.0f / ar;
    rp.offc = PI_F * (1.0f - 2.0f / (2.0f * ar));
    rp.mx = 0.5f + 0.5f * cosf(rp.offc);
    rp.mn = 0.5f + 0.5f * cosf(rp.bar * 90.0f / 180.0f * PI_F + rp.offc);
    return rp;
}

__device__ __forceinline__ float ang_measure(const RowParams& rp, float theta) {
    float cfv = 0.5f + 0.5f * cosf(rp.bar * theta / 180.0f * PI_F + rp.offc);
    float r = (cfv - rp.mn) / (rp.mx - rp.mn) * (1.0f - rp.av) + rp.av;
    return isnan(r) ? 0.0f : r;
}

// align in exact reference op order: (s**1 * iou**5) * ang**3, left-assoc
__device__ __forceinline__ float align_fn(float s, float iou, float r) {
    float iou2 = iou * iou;
    float iou5 = (iou2 * iou2) * iou;
    float r3 = (r * r) * r;
    return (s * iou5) * r3;
}

__device__ __forceinline__ void ins13(u64* arr, u64 key) {
#pragma unroll
    for (int jj = 0; jj < TOPK; jj++) {
        u64 hi = arr[jj] > key ? arr[jj] : key;
        u64 lo = arr[jj] > key ? key : arr[jj];
        arr[jj] = hi;
        key = lo;
    }
}

__global__ void k0_init(int* cnt, int* assign1, u32* pam, u32* pov, int BA, int BN) {
    int t = blockIdx.x * blockDim.x + threadIdx.x;
    if (t < BA) { cnt[t] = 0; assign1[t] = -1; }
    if (t < BN) { pam[t] = 0x80000000u; pov[t] = 0x80000000u; } // ord(+0.0f)
}

__global__ __launch_bounds__(K1_THREADS)
void k1_topk(const float* __restrict__ scores, const float* __restrict__ pbox,
             const float* __restrict__ pang, const float* __restrict__ anc,
             const int* __restrict__ glab, const float* __restrict__ gbox,
             const float* __restrict__ gang, const float* __restrict__ mgt,
             int* __restrict__ cnt, int* __restrict__ assign1,
             int bs, int A, int n, int C) {
    int j = blockIdx.x;
    // XCD clustering: same-batch blocks land on the same XCD (j%8 == b%8 for bs=16)
    int b = j % bs;
    int i = j / bs;
    int bi = b * n + i;
    int tid = threadIdx.x;
    int lane = tid & 63, wv = tid >> 6;

    float mg = mgt[bi];
    if (!(mg > 0.0f)) return;   // block-uniform: no barrier hazard

    float4 g = ((const float4*)gbox)[bi];
    int lab = glab[bi];
    float ga = gang[bi];
    RowParams rp = row_params(g);

    const float4* pb = ((const float4*)pbox) + (size_t)b * A;
    const float* pa = pang + (size_t)b * A;
    const float2* ac = (const float2*)anc;
    const float* sc = scores + (size_t)b * A * C + lab;

    u64 arr[TOPK];
#pragma unroll
    for (int jj = 0; jj < TOPK; jj++) arr[jj] = 0ull;
    u64 zkey = 0ull;  // thread's lowest-index exact-+0 candidate

    // ---- iteration 0 (anchors [0, K1_THREADS)): full reference-exact path ----
    bool zc0 = false;
    {
        int a = tid;
        float4 p = pb[a];
        float iou = iou_fn(g, p);
        float2 apt = ac[a];
        float mnv = fminf(fminf(apt.x - g.x, apt.y - g.y), fminf(g.z - apt.x, g.w - apt.y));
        bool hot = (mnv > 1e-9f) && iou > 0.0f;
        float th = fabsf(ga - pa[a]);
        float r = ang_measure(rp, th);
        // v = align*in_gts, align=(s*iou^5)*r^3, s>0. v>0: positive;
        // v==+0: zero cand (index-ranked); v<0/-0: never selectable.
        if (hot && r > 0.0f) {
            float s = sc[(size_t)a * C];
            float v = align_fn(s, iou, r);
            if (v > 0.0f) {
                u64 key = ((u64)ford(v) << 32) | (u64)(0xFFFFFFFFu - (u32)a);
                ins13(arr, key);
            } else {
                zc0 = true;  // underflow / s==0 -> exactly +0
            }
        } else {
            zc0 = (r >= 0.0f);  // v == sign(r)*0
        }
        if (zc0) zkey = (0x80000000ull << 32) | (u64)(0xFFFFFFFFu - (u32)a);
    }
    // block-wide count of window-0 zero candidates
    __shared__ int s_zc[K1_WAVES];
    u64 bal = __ballot(zc0);
    if (lane == 0) s_zc[wv] = __popcll(bal);
    __syncthreads();
    int zc = 0;
#pragma unroll
    for (int w = 0; w < K1_WAVES; w++) zc += s_zc[w];

    if (zc >= TOPK) {
        // FAST: >=13 zeros in window 0 => all fill winners come from window 0
        // (positives rank above all +0 zeros; any later zero loses to >=13
        // lower-index zeros). Main loop tracks positives only -> no
        // loop-carried state, fully pipelineable.
        for (int a = tid + K1_THREADS; a < A; a += K1_THREADS) {
            float4 p = pb[a];
            float iou = iou_fn(g, p);
            float2 apt = ac[a];
            float mnv = fminf(fminf(apt.x - g.x, apt.y - g.y), fminf(g.z - apt.x, g.w - apt.y));
            bool hot = (mnv > 1e-9f) && iou > 0.0f;
            if (hot) {
                float th = fabsf(ga - pa[a]);
                float r = ang_measure(rp, th);
                if (r > 0.0f) {
                    float s = sc[(size_t)a * C];   // scattered load, rare path
                    float v = align_fn(s, iou, r);
                    if (v > 0.0f) {
                        u64 key = ((u64)ford(v) << 32) | (u64)(0xFFFFFFFFu - (u32)a);
                        if (key > arr[TOPK - 1]) ins13(arr, key);
                    }
                }
            }
        }
    } else {
        // SLOW fallback (pathological): reference-exact full loop with zkey
        for (int a = tid + K1_THREADS; a < A; a += K1_THREADS) {
            float4 p = pb[a];
            float iou = iou_fn(g, p);
            float2 apt = ac[a];
            float mnv = fminf(fminf(apt.x - g.x, apt.y - g.y), fminf(g.z - apt.x, g.w - apt.y));
            bool hot = (mnv > 1e-9f) && iou > 0.0f;
            float th = fabsf(ga - pa[a]);
            float r = ang_measure(rp, th);
            bool zeroCand;
            if (hot && r > 0.0f) {
                float s = sc[(size_t)a * C];
                float v = align_fn(s, iou, r);
                if (v > 0.0f) {
                    zeroCand = false;
                    u64 key = ((u64)ford(v) << 32) | (u64)(0xFFFFFFFFu - (u32)a);
                    if (key > arr[TOPK - 1]) ins13(arr, key);
                } else {
                    zeroCand = true;
                }
            } else {
                zeroCand = (r >= 0.0f);
            }
            if (zeroCand && zkey == 0ull) {
                zkey = (0x80000000ull << 32) | (u64)(0xFFFFFFFFu - (u32)a);
            }
        }
    }
    // merge the single zero candidate
    if (zkey > arr[TOPK - 1]) ins13(arr, zkey);

    // 13 rounds of block-wide max; wave shuffle + per-wave LDS slot
    __shared__ u64 sh[2][K1_WAVES];
    for (int round = 0; round < TOPK; round++) {
        u64 head = arr[0];
        u64 m = head;
#pragma unroll
        for (int st = 32; st > 0; st >>= 1) {
            u64 o = __shfl_xor(m, st, 64);
            if (o > m) m = o;
        }
        if (lane == 0) sh[round & 1][wv] = m;
        __syncthreads();
        u64 win = sh[round & 1][0];
#pragma unroll
        for (int w = 1; w < K1_WAVES; w++) {
            u64 o = sh[round & 1][w]; if (o > win) win = o;
        }
        if (head == win && win != 0ull) {  // unique key -> exactly one winner
#pragma unroll
            for (int jj = 0; jj < TOPK - 1; jj++) arr[jj] = arr[jj + 1];
            arr[TOPK - 1] = 0ull;
            int a = (int)(0xFFFFFFFFu - (u32)(win & 0xFFFFFFFFull));
            float2 apt = ac[a];
            float mnv = fminf(fminf(apt.x - g.x, apt.y - g.y), fminf(g.z - apt.x, g.w - apt.y));
            if (mnv > 1e-9f) {  // mask_pos = mask_topk * in_gts * mask_gt
                atomicAdd(&cnt[(size_t)b * A + a], 1);
                atomicMax(&assign1[(size_t)b * A + a], i);
            }
        }
    }
}

__global__ __launch_bounds__(256)
void k2_resolve(const float* __restrict__ scores, const float* __restrict__ pbox,
                const float* __restrict__ pang, const int* __restrict__ glab,
                const float* __restrict__ gbox, const float* __restrict__ gang,
                const int* __restrict__ cnt, const int* __restrict__ assign1,
                int* __restrict__ assign, float* __restrict__ alignv,
                u32* __restrict__ pam, u32* __restrict__ pov,
                int bs, int A, int n, int C) {
    int t = blockIdx.x * blockDim.x + threadIdx.x;
    if (t >= bs * A) return;
    int b = t / A;
    int c = cnt[t];
    int asg = -1;
    float alv = 0.0f;
    if (c > 0) {
        float4 p = ((const float4*)pbox)[t];
        if (c == 1) {
            asg = assign1[t];
        } else {
            // reference: overlaps.argmax(1) over ALL gt rows, first-max tie-break
            float best = -1.0f;
            asg = 0;
            for (int i = 0; i < n; i++) {
                float4 gi = ((const float4*)gbox)[b * n + i];
                float io = iou_fn(gi, p);
                if (io > best) { best = io; asg = i; }
            }
        }
        float4 g = ((const float4*)gbox)[b * n + asg];
        RowParams rp = row_params(g);
        float iou = iou_fn(g, p);
        float th = fabsf(gang[b * n + asg] - pang[t]);
        float r = ang_measure(rp, th);
        float s = scores[(size_t)t * C + glab[b * n + asg]];
        alv = align_fn(s, iou, r);
        atomicMax(&pam[b * n + asg], ford(alv));
        atomicMax(&pov[b * n + asg], ford(iou));
    }
    assign[t] = asg;
    alignv[t] = alv;
}

__global__ __launch_bounds__(256)
void k3_out(const int* __restrict__ glab, const float* __restrict__ gbox,
            const float* __restrict__ gang, const int* __restrict__ assign,
            const float* __restrict__ alignv, const u32* __restrict__ pam,
            const u32* __restrict__ pov, float* __restrict__ out,
            int bs, int A, int n, int C) {
    __shared__ float s_nv[256];
    __shared__ int s_lf[256];
    int tid = threadIdx.x;
    int base = blockIdx.x * 256;
    int t = base + tid;
    int BA = bs * A;

    if (t < BA) {
        int b = t / A;
        int asg = assign[t];
        bool fg = asg >= 0;
        int tgt = fg ? asg : 0;  // argmax of all-zero column -> row 0
        int lb = glab[b * n + tgt];
        if (lb < 0) lb = 0;

        float* o_tlab = out;
        float* o_tbb = out + BA;
        float* o_tang = out + (size_t)BA * 5;
        float* o_fg = out + (size_t)BA * 6 + (size_t)BA * C;

        o_tlab[t] = (float)lb;
        ((float4*)o_tbb)[t] = ((const float4*)gbox)[b * n + tgt];
        o_tang[t] = gang[b * n + tgt];
        o_fg[t] = fg ? 1.0f : 0.0f;

        float nv = 0.0f;
        if (fg) {
            float pamv = funord(pam[b * n + asg]);
            float povv = funord(pov[b * n + asg]);
            float vv = (alignv[t] * povv) / (pamv + 1e-9f);
            nv = fmaxf(vv, 0.0f);  // 59 other rows contribute exactly 0 to the max
        }
        s_nv[tid] = nv;
        s_lf[tid] = fg ? lb : -1;
    } else {
        s_nv[tid] = 0.0f;
        s_lf[tid] = -1;
    }
    __syncthreads();

    // ts: coalesced float4 writes, (anchor, class-quad) with quad fastest
    int Q = C / 4;  // 20
    int nA = min(256, BA - base);
    if (nA <= 0) return;
    int total = nA * Q;
    float4* o_ts = (float4*)(out + (size_t)BA * 6) + (size_t)base * Q;
    for (int idx = tid; idx < total; idx += 256) {
        int tl = idx / Q;
        int q = idx - tl * Q;
        float nv = s_nv[tl];
        int lf = s_lf[tl];
        int cb = q * 4;
        float4 o;
        o.x = (lf == cb) ? nv : 0.0f;
        o.y = (lf == cb + 1) ? nv : 0.0f;
        o.z = (lf == cb + 2) ? nv : 0.0f;
        o.w = (lf == cb + 3) ? nv : 0.0f;
        o_ts[idx] = o;
    }
}

extern "C" void kernel_launch(void* const* d_in, const int* in_sizes, int n_in,
                              void* d_out, int out_size, void* d_ws, size_t ws_size,
                              hipStream_t stream) {
    const float* scores = (const float*)d_in[0];
    const float* pbox = (const float*)d_in[1];
    const float* pang = (const float*)d_in[2];
    const float* anc = (const float*)d_in[3];
    const int* glab = (const int*)d_in[4];
    const float* gbox = (const float*)d_in[5];
    const float* gang = (const float*)d_in[6];
    const float* mgt = (const float*)d_in[7];

    const int C = 80;
    int A = in_sizes[3] / 2;
    int bs = in_sizes[0] / (A * C);
    int n = in_sizes[4] / bs;
    int BA = bs * A;
    int BN = bs * n;

    char* ws = (char*)d_ws;
    int* cnt = (int*)ws;        ws += sizeof(int) * (size_t)BA;
    int* assign1 = (int*)ws;    ws += sizeof(int) * (size_t)BA;
    int* assign = (int*)ws;     ws += sizeof(int) * (size_t)BA;
    float* alignv = (float*)ws; ws += sizeof(float) * (size_t)BA;
    u32* pam = (u32*)ws;        ws += sizeof(u32) * (size_t)BN;
    u32* pov = (u32*)ws;        ws += sizeof(u32) * (size_t)BN;

    k0_init<<<(BA + 255) / 256, 256, 0, stream>>>(cnt, assign1, pam, pov, BA, BN);
    k1_topk<<<BN, K1_THREADS, 0, stream>>>(scores, pbox, pang, anc, glab, gbox, gang, mgt,
                                           cnt, assign1, bs, A, n, C);
    k2_resolve<<<(BA + 255) / 256, 256, 0, stream>>>(scores, pbox, pang, glab, gbox, gang,
                                                     cnt, assign1, assign, alignv, pam, pov,
                                                     bs, A, n, C);
    k3_out<<<(BA + 255) / 256, 256, 0, stream>>>(glab, gbox, gang, assign, alignv, pam, pov,
                                                 (float*)d_out, bs, A, n, C);
}

// Round 6
// 181.181 us; speedup vs baseline: 1.0247x; 1.0247x over previous
//
#include <hip/hip_runtime.h>
#include <math.h>

#define TOPK 13
#define PI_F 3.14159265358979323846f
#define K1_THREADS 512
#define K1_WAVES (K1_THREADS / 64)
#define HOTCAP 4096

typedef unsigned int u32;
typedef unsigned long long u64;

// monotone float -> uint mapping matching XLA total order
__device__ __forceinline__ u32 ford(float f) {
    u32 u = __float_as_uint(f);
    return (u & 0x80000000u) ? ~u : (u | 0x80000000u);
}
__device__ __forceinline__ float funord(u32 o) {
    u32 u = (o & 0x80000000u) ? (o & 0x7FFFFFFFu) : ~o;
    return __uint_as_float(u);
}

__device__ __forceinline__ float iou_fn(float4 g, float4 p) {
    float ltx = fmaxf(g.x, p.x), lty = fmaxf(g.y, p.y);
    float rbx = fminf(g.z, p.z), rby = fminf(g.w, p.w);
    float inter = fmaxf(rbx - ltx, 0.0f) * fmaxf(rby - lty, 0.0f);
    float a1 = fmaxf(g.z - g.x, 0.0f) * fmaxf(g.w - g.y, 0.0f);
    float a2 = fmaxf(p.z - p.x, 0.0f) * fmaxf(p.w - p.y, 0.0f);
    return inter / (((a1 + a2) - inter) + 1e-9f);
}

struct RowParams { float av, bar, offc, mx, mn; };

__device__ __forceinline__ RowParams row_params(float4 g) {
    float w = g.z - g.x, h = g.w - g.y;
    float ar = w / (h + 1e-5f);
    float ia = 1.0f / ar;
    RowParams rp;
    rp.av = ia / (2.0f - ia);
    rp.bar = 2.0f / ar;
    rp.offc = PI_F * (1.0f - 2.0f / (2.0f * ar));
    rp.mx = 0.5f + 0.5f * cosf(rp.offc);
    rp.mn = 0.5f + 0.5f * cosf(rp.bar * 90.0f / 180.0f * PI_F + rp.offc);
    return rp;
}

__device__ __forceinline__ float ang_measure(const RowParams& rp, float theta) {
    float cfv = 0.5f + 0.5f * cosf(rp.bar * theta / 180.0f * PI_F + rp.offc);
    float r = (cfv - rp.mn) / (rp.mx - rp.mn) * (1.0f - rp.av) + rp.av;
    return isnan(r) ? 0.0f : r;
}

// align in exact reference op order: (s**1 * iou**5) * ang**3, left-assoc
__device__ __forceinline__ float align_fn(float s, float iou, float r) {
    float iou2 = iou * iou;
    float iou5 = (iou2 * iou2) * iou;
    float r3 = (r * r) * r;
    return (s * iou5) * r3;
}

__device__ __forceinline__ void ins13(u64* arr, u64 key) {
#pragma unroll
    for (int jj = 0; jj < TOPK; jj++) {
        u64 hi = arr[jj] > key ? arr[jj] : key;
        u64 lo = arr[jj] > key ? key : arr[jj];
        arr[jj] = hi;
        key = lo;
    }
}

__global__ void k0_init(int* cnt, int* assign1, u32* pam, u32* pov, int BA, int BN) {
    int t = blockIdx.x * blockDim.x + threadIdx.x;
    if (t < BA) { cnt[t] = 0; assign1[t] = -1; }
    if (t < BN) { pam[t] = 0x80000000u; pov[t] = 0x80000000u; } // ord(+0.0f)
}

__global__ __launch_bounds__(K1_THREADS)
void k1_topk(const float* __restrict__ scores, const float* __restrict__ pbox,
             const float* __restrict__ pang, const float* __restrict__ anc,
             const int* __restrict__ glab, const float* __restrict__ gbox,
             const float* __restrict__ gang, const float* __restrict__ mgt,
             int* __restrict__ cnt, int* __restrict__ assign1,
             int bs, int A, int n, int C) {
    int j = blockIdx.x;
    // XCD clustering: same-batch blocks land on the same XCD (j%8 == b%8 for bs=16)
    int b = j % bs;
    int i = j / bs;
    int bi = b * n + i;
    int tid = threadIdx.x;
    int lane = tid & 63, wv = tid >> 6;

    float mg = mgt[bi];
    if (!(mg > 0.0f)) return;   // block-uniform early exit

    float4 g = ((const float4*)gbox)[bi];
    int lab = glab[bi];
    float ga = gang[bi];
    RowParams rp = row_params(g);

    const float4* pb = ((const float4*)pbox) + (size_t)b * A;
    const float* pa = pang + (size_t)b * A;
    const float2* ac = (const float2*)anc;
    const float* sc = scores + (size_t)b * A * C + lab;

    u64 arr[TOPK];
#pragma unroll
    for (int jj = 0; jj < TOPK; jj++) arr[jj] = 0ull;
    u64 zkey = 0ull;  // thread's lowest-index exact-+0 candidate

    __shared__ u32 s_hot[HOTCAP];
    __shared__ int s_nhot;
    __shared__ int s_zc[K1_WAVES];

    // ---- window 0 (anchors [0, K1_THREADS)): full reference-exact path ----
    bool zc0 = false;
    {
        int a = tid;
        float4 p = pb[a];
        float iou = iou_fn(g, p);
        float2 apt = ac[a];
        float mnv = fminf(fminf(apt.x - g.x, apt.y - g.y), fminf(g.z - apt.x, g.w - apt.y));
        bool hot = (mnv > 1e-9f) && iou > 0.0f;
        float th = fabsf(ga - pa[a]);
        float r = ang_measure(rp, th);
        // v = align*in_gts, align=(s*iou^5)*r^3, s>0. v>0: positive;
        // v==+0: zero cand (index-ranked); v<0/-0: never selectable.
        if (hot && r > 0.0f) {
            float s = sc[(size_t)a * C];
            float v = align_fn(s, iou, r);
            if (v > 0.0f) {
                u64 key = ((u64)ford(v) << 32) | (u64)(0xFFFFFFFFu - (u32)a);
                ins13(arr, key);
            } else {
                zc0 = true;  // underflow / s==0 -> exactly +0
            }
        } else {
            zc0 = (r >= 0.0f);  // v == sign(r)*0
        }
        if (zc0) zkey = (0x80000000ull << 32) | (u64)(0xFFFFFFFFu - (u32)a);
    }
    // block-wide count of window-0 zero candidates
    u64 bal0 = __ballot(zc0);
    if (lane == 0) s_zc[wv] = __popcll(bal0);
    if (tid == 0) s_nhot = 0;
    __syncthreads();
    int zc = 0;
#pragma unroll
    for (int w = 0; w < K1_WAVES; w++) zc += s_zc[w];

    bool useSlow;
    int nh = 0;
    if (zc >= TOPK) {
        // Phase A: branchless stream; compact hot anchors (a>=512) into LDS.
        // No cosf, no data-dependent arithmetic -> compiler can pipeline loads.
        for (int a = tid + K1_THREADS; a < A; a += K1_THREADS) {
            float4 p = pb[a];
            float iou = iou_fn(g, p);
            float2 apt = ac[a];
            float mnv = fminf(fminf(apt.x - g.x, apt.y - g.y), fminf(g.z - apt.x, g.w - apt.y));
            bool hot = (mnv > 1e-9f) && iou > 0.0f;
            u64 bal = __ballot(hot);
            if (bal) {  // wave-aggregated append: one LDS atomic per wave
                int cnt_w = __popcll(bal);
                int lead = __ffsll((unsigned long long)bal) - 1;
                int basei = 0;
                if (lane == lead) basei = atomicAdd(&s_nhot, cnt_w);
                basei = __shfl(basei, lead, 64);
                if (hot) {
                    int rank = __popcll(bal & ((lane == 63) ? 0x7FFFFFFFFFFFFFFFull
                                                            : ((1ull << lane) - 1)));
                    int pos = basei + rank;
                    if (pos < HOTCAP) s_hot[pos] = (u32)a;
                }
            }
        }
        __syncthreads();
        nh = s_nhot;
        useSlow = (nh > HOTCAP);   // overflow: fall back to exact rescan
        if (useSlow) nh = 0;
    } else {
        useSlow = true;            // pathological: <13 zeros in window 0
    }

    if (!useSlow) {
        // Phase B: exact reference math on the tiny hot list (zeros at a>=512
        // can never win: >=13 lower-index zeros exist in window 0).
        for (int t2 = tid; t2 < nh; t2 += K1_THREADS) {
            int a = (int)s_hot[t2];
            float4 p = pb[a];
            float iou = iou_fn(g, p);
            float th = fabsf(ga - pa[a]);
            float r = ang_measure(rp, th);
            if (r > 0.0f) {
                float s = sc[(size_t)a * C];
                float v = align_fn(s, iou, r);
                if (v > 0.0f) {
                    u64 key = ((u64)ford(v) << 32) | (u64)(0xFFFFFFFFu - (u32)a);
                    if (key > arr[TOPK - 1]) ins13(arr, key);
                }
            }
        }
    } else {
        // SLOW fallback: reference-exact full loop with zkey tracking
        for (int a = tid + K1_THREADS; a < A; a += K1_THREADS) {
            float4 p = pb[a];
            float iou = iou_fn(g, p);
            float2 apt = ac[a];
            float mnv = fminf(fminf(apt.x - g.x, apt.y - g.y), fminf(g.z - apt.x, g.w - apt.y));
            bool hot = (mnv > 1e-9f) && iou > 0.0f;
            float th = fabsf(ga - pa[a]);
            float r = ang_measure(rp, th);
            bool zeroCand;
            if (hot && r > 0.0f) {
                float s = sc[(size_t)a * C];
                float v = align_fn(s, iou, r);
                if (v > 0.0f) {
                    zeroCand = false;
                    u64 key = ((u64)ford(v) << 32) | (u64)(0xFFFFFFFFu - (u32)a);
                    if (key > arr[TOPK - 1]) ins13(arr, key);
                } else {
                    zeroCand = true;
                }
            } else {
                zeroCand = (r >= 0.0f);
            }
            if (zeroCand && zkey == 0ull) {
                zkey = (0x80000000ull << 32) | (u64)(0xFFFFFFFFu - (u32)a);
            }
        }
    }
    // merge the single zero candidate
    if (zkey > arr[TOPK - 1]) ins13(arr, zkey);

    // 13 rounds of block-wide max; wave shuffle + per-wave LDS slot
    __shared__ u64 sh[2][K1_WAVES];
    for (int round = 0; round < TOPK; round++) {
        u64 head = arr[0];
        u64 m = head;
#pragma unroll
        for (int st = 32; st > 0; st >>= 1) {
            u64 o = __shfl_xor(m, st, 64);
            if (o > m) m = o;
        }
        if (lane == 0) sh[round & 1][wv] = m;
        __syncthreads();
        u64 win = sh[round & 1][0];
#pragma unroll
        for (int w = 1; w < K1_WAVES; w++) {
            u64 o = sh[round & 1][w]; if (o > win) win = o;
        }
        if (head == win && win != 0ull) {  // unique key -> exactly one winner
#pragma unroll
            for (int jj = 0; jj < TOPK - 1; jj++) arr[jj] = arr[jj + 1];
            arr[TOPK - 1] = 0ull;
            int a = (int)(0xFFFFFFFFu - (u32)(win & 0xFFFFFFFFull));
            float2 apt = ac[a];
            float mnv = fminf(fminf(apt.x - g.x, apt.y - g.y), fminf(g.z - apt.x, g.w - apt.y));
            if (mnv > 1e-9f) {  // mask_pos = mask_topk * in_gts * mask_gt
                atomicAdd(&cnt[(size_t)b * A + a], 1);
                atomicMax(&assign1[(size_t)b * A + a], i);
            }
        }
    }
}

__global__ __launch_bounds__(256)
void k2_resolve(const float* __restrict__ scores, const float* __restrict__ pbox,
                const float* __restrict__ pang, const int* __restrict__ glab,
                const float* __restrict__ gbox, const float* __restrict__ gang,
                const int* __restrict__ cnt, const int* __restrict__ assign1,
                int* __restrict__ assign, float* __restrict__ alignv,
                u32* __restrict__ pam, u32* __restrict__ pov,
                int bs, int A, int n, int C) {
    int t = blockIdx.x * blockDim.x + threadIdx.x;
    if (t >= bs * A) return;
    int b = t / A;
    int c = cnt[t];
    int asg = -1;
    float alv = 0.0f;
    if (c > 0) {
        float4 p = ((const float4*)pbox)[t];
        if (c == 1) {
            asg = assign1[t];
        } else {
            // reference: overlaps.argmax(1) over ALL gt rows, first-max tie-break
            float best = -1.0f;
            asg = 0;
            for (int i = 0; i < n; i++) {
                float4 gi = ((const float4*)gbox)[b * n + i];
                float io = iou_fn(gi, p);
                if (io > best) { best = io; asg = i; }
            }
        }
        float4 g = ((const float4*)gbox)[b * n + asg];
        RowParams rp = row_params(g);
        float iou = iou_fn(g, p);
        float th = fabsf(gang[b * n + asg] - pang[t]);
        float r = ang_measure(rp, th);
        float s = scores[(size_t)t * C + glab[b * n + asg]];
        alv = align_fn(s, iou, r);
        atomicMax(&pam[b * n + asg], ford(alv));
        atomicMax(&pov[b * n + asg], ford(iou));
    }
    assign[t] = asg;
    alignv[t] = alv;
}

__global__ __launch_bounds__(256)
void k3_out(const int* __restrict__ glab, const float* __restrict__ gbox,
            const float* __restrict__ gang, const int* __restrict__ assign,
            const float* __restrict__ alignv, const u32* __restrict__ pam,
            const u32* __restrict__ pov, float* __restrict__ out,
            int bs, int A, int n, int C) {
    __shared__ float s_nv[256];
    __shared__ int s_lf[256];
    int tid = threadIdx.x;
    int base = blockIdx.x * 256;
    int t = base + tid;
    int BA = bs * A;

    if (t < BA) {
        int b = t / A;
        int asg = assign[t];
        bool fg = asg >= 0;
        int tgt = fg ? asg : 0;  // argmax of all-zero column -> row 0
        int lb = glab[b * n + tgt];
        if (lb < 0) lb = 0;

        float* o_tlab = out;
        float* o_tbb = out + BA;
        float* o_tang = out + (size_t)BA * 5;
        float* o_fg = out + (size_t)BA * 6 + (size_t)BA * C;

        o_tlab[t] = (float)lb;
        ((float4*)o_tbb)[t] = ((const float4*)gbox)[b * n + tgt];
        o_tang[t] = gang[b * n + tgt];
        o_fg[t] = fg ? 1.0f : 0.0f;

        float nv = 0.0f;
        if (fg) {
            float pamv = funord(pam[b * n + asg]);
            float povv = funord(pov[b * n + asg]);
            float vv = (alignv[t] * povv) / (pamv + 1e-9f);
            nv = fmaxf(vv, 0.0f);  // 59 other rows contribute exactly 0 to the max
        }
        s_nv[tid] = nv;
        s_lf[tid] = fg ? lb : -1;
    } else {
        s_nv[tid] = 0.0f;
        s_lf[tid] = -1;
    }
    __syncthreads();

    // ts: coalesced float4 writes, (anchor, class-quad) with quad fastest
    int Q = C / 4;  // 20
    int nA = min(256, BA - base);
    if (nA <= 0) return;
    int total = nA * Q;
    float4* o_ts = (float4*)(out + (size_t)BA * 6) + (size_t)base * Q;
    for (int idx = tid; idx < total; idx += 256) {
        int tl = idx / Q;
        int q = idx - tl * Q;
        float nv = s_nv[tl];
        int lf = s_lf[tl];
        int cb = q * 4;
        float4 o;
        o.x = (lf == cb) ? nv : 0.0f;
        o.y = (lf == cb + 1) ? nv : 0.0f;
        o.z = (lf == cb + 2) ? nv : 0.0f;
        o.w = (lf == cb + 3) ? nv : 0.0f;
        o_ts[idx] = o;
    }
}

extern "C" void kernel_launch(void* const* d_in, const int* in_sizes, int n_in,
                              void* d_out, int out_size, void* d_ws, size_t ws_size,
                              hipStream_t stream) {
    const float* scores = (const float*)d_in[0];
    const float* pbox = (const float*)d_in[1];
    const float* pang = (const float*)d_in[2];
    const float* anc = (const float*)d_in[3];
    const int* glab = (const int*)d_in[4];
    const float* gbox = (const float*)d_in[5];
    const float* gang = (const float*)d_in[6];
    const float* mgt = (const float*)d_in[7];

    const int C = 80;
    int A = in_sizes[3] / 2;
    int bs = in_sizes[0] / (A * C);
    int n = in_sizes[4] / bs;
    int BA = bs * A;
    int BN = bs * n;

    char* ws = (char*)d_ws;
    int* cnt = (int*)ws;        ws += sizeof(int) * (size_t)BA;
    int* assign1 = (int*)ws;    ws += sizeof(int) * (size_t)BA;
    int* assign = (int*)ws;     ws += sizeof(int) * (size_t)BA;
    float* alignv = (float*)ws; ws += sizeof(float) * (size_t)BA;
    u32* pam = (u32*)ws;        ws += sizeof(u32) * (size_t)BN;
    u32* pov = (u32*)ws;        ws += sizeof(u32) * (size_t)BN;

    k0_init<<<(BA + 255) / 256, 256, 0, stream>>>(cnt, assign1, pam, pov, BA, BN);
    k1_topk<<<BN, K1_THREADS, 0, stream>>>(scores, pbox, pang, anc, glab, gbox, gang, mgt,
                                           cnt, assign1, bs, A, n, C);
    k2_resolve<<<(BA + 255) / 256, 256, 0, stream>>>(scores, pbox, pang, glab, gbox, gang,
                                                     cnt, assign1, assign, alignv, pam, pov,
                                                     bs, A, n, C);
    k3_out<<<(BA + 255) / 256, 256, 0, stream>>>(glab, gbox, gang, assign, alignv, pam, pov,
                                                 (float*)d_out, bs, A, n, C);
}

// Round 7
// 174.678 us; speedup vs baseline: 1.0628x; 1.0372x over previous
//
#include <hip/hip_runtime.h>
#include <math.h>

#define TOPK 13
#define PI_F 3.14159265358979323846f
#define K1_THREADS 256
#define K1_WAVES (K1_THREADS / 64)
#define GC 10
#define INV_CELL (1.0f / 64.0f)

typedef unsigned int u32;
typedef unsigned long long u64;

// monotone float -> uint mapping matching XLA total order
__device__ __forceinline__ u32 ford(float f) {
    u32 u = __float_as_uint(f);
    return (u & 0x80000000u) ? ~u : (u | 0x80000000u);
}
__device__ __forceinline__ float funord(u32 o) {
    u32 u = (o & 0x80000000u) ? (o & 0x7FFFFFFFu) : ~o;
    return __uint_as_float(u);
}

__device__ __forceinline__ float iou_fn(float4 g, float4 p) {
    float ltx = fmaxf(g.x, p.x), lty = fmaxf(g.y, p.y);
    float rbx = fminf(g.z, p.z), rby = fminf(g.w, p.w);
    float inter = fmaxf(rbx - ltx, 0.0f) * fmaxf(rby - lty, 0.0f);
    float a1 = fmaxf(g.z - g.x, 0.0f) * fmaxf(g.w - g.y, 0.0f);
    float a2 = fmaxf(p.z - p.x, 0.0f) * fmaxf(p.w - p.y, 0.0f);
    return inter / (((a1 + a2) - inter) + 1e-9f);
}

struct RowParams { float av, bar, offc, mx, mn; };

__device__ __forceinline__ RowParams row_params(float4 g) {
    float w = g.z - g.x, h = g.w - g.y;
    float ar = w / (h + 1e-5f);
    float ia = 1.0f / ar;
    RowParams rp;
    rp.av = ia / (2.0f - ia);
    rp.bar = 2.0f / ar;
    rp.offc = PI_F * (1.0f - 2.0f / (2.0f * ar));
    rp.mx = 0.5f + 0.5f * cosf(rp.offc);
    rp.mn = 0.5f + 0.5f * cosf(rp.bar * 90.0f / 180.0f * PI_F + rp.offc);
    return rp;
}

__device__ __forceinline__ float ang_measure(const RowParams& rp, float theta) {
    float cfv = 0.5f + 0.5f * cosf(rp.bar * theta / 180.0f * PI_F + rp.offc);
    float r = (cfv - rp.mn) / (rp.mx - rp.mn) * (1.0f - rp.av) + rp.av;
    return isnan(r) ? 0.0f : r;
}

// align in exact reference op order: (s**1 * iou**5) * ang**3, left-assoc
__device__ __forceinline__ float align_fn(float s, float iou, float r) {
    float iou2 = iou * iou;
    float iou5 = (iou2 * iou2) * iou;
    float r3 = (r * r) * r;
    return (s * iou5) * r3;
}

__device__ __forceinline__ void ins13(u64* arr, u64 key) {
#pragma unroll
    for (int jj = 0; jj < TOPK; jj++) {
        u64 hi = arr[jj] > key ? arr[jj] : key;
        u64 lo = arr[jj] > key ? key : arr[jj];
        arr[jj] = hi;
        key = lo;
    }
}

__global__ void k0_init(int* cnt, int* assign1, u32* pam, u32* pov, int BA, int BN) {
    int t = blockIdx.x * blockDim.x + threadIdx.x;
    if (t < BA) { cnt[t] = 0; assign1[t] = -1; }
    if (t < BN) { pam[t] = 0x80000000u; pov[t] = 0x80000000u; } // ord(+0.0f)
}

// Single-block anchor->cell CSR build (anchors are batch-independent).
__global__ __launch_bounds__(1024)
void k_grid(const float* __restrict__ anc, int A,
            int* __restrict__ cell_start, float2* __restrict__ cell_pts,
            u32* __restrict__ cell_idx) {
    __shared__ int s_cnt[GC * GC];
    __shared__ int s_off[GC * GC + 1];
    int tid = threadIdx.x;
    if (tid < GC * GC) s_cnt[tid] = 0;
    __syncthreads();
    const float2* ac = (const float2*)anc;
    for (int a = tid; a < A; a += 1024) {
        float2 p = ac[a];
        int cx = min(GC - 1, max(0, (int)(p.x * INV_CELL)));
        int cy = min(GC - 1, max(0, (int)(p.y * INV_CELL)));
        atomicAdd(&s_cnt[cy * GC + cx], 1);
    }
    __syncthreads();
    if (tid == 0) {
        int acc = 0;
        for (int c = 0; c < GC * GC; c++) { s_off[c] = acc; acc += s_cnt[c]; }
        s_off[GC * GC] = acc;
    }
    __syncthreads();
    if (tid <= GC * GC) cell_start[tid] = s_off[tid];
    if (tid < GC * GC) s_cnt[tid] = s_off[tid];  // running offsets
    __syncthreads();
    for (int a = tid; a < A; a += 1024) {
        float2 p = ac[a];
        int cx = min(GC - 1, max(0, (int)(p.x * INV_CELL)));
        int cy = min(GC - 1, max(0, (int)(p.y * INV_CELL)));
        int pos = atomicAdd(&s_cnt[cy * GC + cx], 1);
        cell_pts[pos] = p;
        cell_idx[pos] = (u32)a;
    }
}

__global__ __launch_bounds__(K1_THREADS)
void k1_topk(const float* __restrict__ scores, const float* __restrict__ pbox,
             const float* __restrict__ pang, const float* __restrict__ anc,
             const int* __restrict__ glab, const float* __restrict__ gbox,
             const float* __restrict__ gang, const float* __restrict__ mgt,
             const int* __restrict__ cell_start, const float2* __restrict__ cell_pts,
             const u32* __restrict__ cell_idx,
             int* __restrict__ cnt, int* __restrict__ assign1,
             int bs, int A, int n, int C) {
    int j = blockIdx.x;
    // XCD clustering: same-batch blocks land on the same XCD (j%8 == b%8 for bs=16)
    int b = j % bs;
    int i = j / bs;
    int bi = b * n + i;
    int tid = threadIdx.x;
    int lane = tid & 63, wv = tid >> 6;

    float mg = mgt[bi];
    if (!(mg > 0.0f)) return;   // block-uniform early exit

    float4 g = ((const float4*)gbox)[bi];
    int lab = glab[bi];
    float ga = gang[bi];
    RowParams rp = row_params(g);

    const float4* pb = ((const float4*)pbox) + (size_t)b * A;
    const float* pa = pang + (size_t)b * A;
    const float2* ac = (const float2*)anc;
    const float* sc = scores + (size_t)b * A * C + lab;

    u64 arr[TOPK];
#pragma unroll
    for (int jj = 0; jj < TOPK; jj++) arr[jj] = 0ull;
    u64 zkey = 0ull;  // thread's lowest-index exact-+0 candidate

    __shared__ int s_zc[K1_WAVES];

    // ---- window 0 (anchors [0, K1_THREADS)): full reference-exact path ----
    bool zc0 = false;
    {
        int a = tid;
        float4 p = pb[a];
        float iou = iou_fn(g, p);
        float2 apt = ac[a];
        float mnv = fminf(fminf(apt.x - g.x, apt.y - g.y), fminf(g.z - apt.x, g.w - apt.y));
        bool hot = (mnv > 1e-9f) && iou > 0.0f;
        float th = fabsf(ga - pa[a]);
        float r = ang_measure(rp, th);
        // v = align*in_gts, align=(s*iou^5)*r^3, s>0. v>0: positive;
        // v==+0: zero cand (index-ranked); v<0/-0: never selectable.
        if (hot && r > 0.0f) {
            float s = sc[(size_t)a * C];
            float v = align_fn(s, iou, r);
            if (v > 0.0f) {
                u64 key = ((u64)ford(v) << 32) | (u64)(0xFFFFFFFFu - (u32)a);
                ins13(arr, key);
            } else {
                zc0 = true;  // underflow / s==0 -> exactly +0
            }
        } else {
            zc0 = (r >= 0.0f);  // v == sign(r)*0
        }
        if (zc0) zkey = (0x80000000ull << 32) | (u64)(0xFFFFFFFFu - (u32)a);
    }
    u64 bal0 = __ballot(zc0);
    if (lane == 0) s_zc[wv] = __popcll(bal0);
    __syncthreads();
    int zc = 0;
#pragma unroll
    for (int w = 0; w < K1_WAVES; w++) zc += s_zc[w];

    if (zc >= TOPK) {
        // FAST: zeros at a>=256 can never win (>=13 lower-index zeros in
        // window 0). Positives need the anchor point strictly inside the gt
        // box -> scan only grid cells overlapping it (coverage exact:
        // g.x < apt.x < g.z  =>  cell_x in [floor(g.x/64), floor(g.z/64)]).
        int cx0 = max(0, (int)floorf(g.x * INV_CELL));
        int cx1 = min(GC - 1, (int)floorf(g.z * INV_CELL));
        int cy0 = max(0, (int)floorf(g.y * INV_CELL));
        int cy1 = min(GC - 1, (int)floorf(g.w * INV_CELL));
        for (int cy = cy0; cy <= cy1; cy++) {
            for (int cx = cx0; cx <= cx1; cx++) {
                int cs = cell_start[cy * GC + cx];
                int ce = cell_start[cy * GC + cx + 1];
                for (int t2 = cs + tid; t2 < ce; t2 += K1_THREADS) {
                    u32 a = cell_idx[t2];
                    if (a < K1_THREADS) continue;  // window 0 already handled
                    float2 apt = cell_pts[t2];
                    float mnv = fminf(fminf(apt.x - g.x, apt.y - g.y),
                                      fminf(g.z - apt.x, g.w - apt.y));
                    if (!(mnv > 1e-9f)) continue;
                    float4 p = pb[a];
                    float iou = iou_fn(g, p);
                    if (!(iou > 0.0f)) continue;
                    float th = fabsf(ga - pa[a]);
                    float r = ang_measure(rp, th);
                    if (r > 0.0f) {
                        float s = sc[(size_t)a * C];
                        float v = align_fn(s, iou, r);
                        if (v > 0.0f) {
                            u64 key = ((u64)ford(v) << 32) | (u64)(0xFFFFFFFFu - a);
                            if (key > arr[TOPK - 1]) ins13(arr, key);
                        }
                    }
                }
            }
        }
    } else {
        // SLOW fallback (pathological): reference-exact full stream with zkey
        for (int a = tid + K1_THREADS; a < A; a += K1_THREADS) {
            float4 p = pb[a];
            float iou = iou_fn(g, p);
            float2 apt = ac[a];
            float mnv = fminf(fminf(apt.x - g.x, apt.y - g.y), fminf(g.z - apt.x, g.w - apt.y));
            bool hot = (mnv > 1e-9f) && iou > 0.0f;
            float th = fabsf(ga - pa[a]);
            float r = ang_measure(rp, th);
            bool zeroCand;
            if (hot && r > 0.0f) {
                float s = sc[(size_t)a * C];
                float v = align_fn(s, iou, r);
                if (v > 0.0f) {
                    zeroCand = false;
                    u64 key = ((u64)ford(v) << 32) | (u64)(0xFFFFFFFFu - (u32)a);
                    if (key > arr[TOPK - 1]) ins13(arr, key);
                } else {
                    zeroCand = true;
                }
            } else {
                zeroCand = (r >= 0.0f);
            }
            if (zeroCand && zkey == 0ull) {
                zkey = (0x80000000ull << 32) | (u64)(0xFFFFFFFFu - (u32)a);
            }
        }
    }
    // merge the single zero candidate
    if (zkey > arr[TOPK - 1]) ins13(arr, zkey);

    // 13 rounds of block-wide max; wave shuffle + per-wave LDS slot
    __shared__ u64 sh[2][K1_WAVES];
    for (int round = 0; round < TOPK; round++) {
        u64 head = arr[0];
        u64 m = head;
#pragma unroll
        for (int st = 32; st > 0; st >>= 1) {
            u64 o = __shfl_xor(m, st, 64);
            if (o > m) m = o;
        }
        if (lane == 0) sh[round & 1][wv] = m;
        __syncthreads();
        u64 win = sh[round & 1][0];
#pragma unroll
        for (int w = 1; w < K1_WAVES; w++) {
            u64 o = sh[round & 1][w]; if (o > win) win = o;
        }
        if (head == win && win != 0ull) {  // unique key -> exactly one winner
#pragma unroll
            for (int jj = 0; jj < TOPK - 1; jj++) arr[jj] = arr[jj + 1];
            arr[TOPK - 1] = 0ull;
            int a = (int)(0xFFFFFFFFu - (u32)(win & 0xFFFFFFFFull));
            float2 apt = ac[a];
            float mnv = fminf(fminf(apt.x - g.x, apt.y - g.y), fminf(g.z - apt.x, g.w - apt.y));
            if (mnv > 1e-9f) {  // mask_pos = mask_topk * in_gts * mask_gt
                atomicAdd(&cnt[(size_t)b * A + a], 1);
                atomicMax(&assign1[(size_t)b * A + a], i);
            }
        }
    }
}

__global__ __launch_bounds__(256)
void k2_resolve(const float* __restrict__ scores, const float* __restrict__ pbox,
                const float* __restrict__ pang, const int* __restrict__ glab,
                const float* __restrict__ gbox, const float* __restrict__ gang,
                const int* __restrict__ cnt, const int* __restrict__ assign1,
                int* __restrict__ assign, float* __restrict__ alignv,
                u32* __restrict__ pam, u32* __restrict__ pov,
                int bs, int A, int n, int C) {
    int t = blockIdx.x * blockDim.x + threadIdx.x;
    if (t >= bs * A) return;
    int b = t / A;
    int c = cnt[t];
    int asg = -1;
    float alv = 0.0f;
    if (c > 0) {
        float4 p = ((const float4*)pbox)[t];
        if (c == 1) {
            asg = assign1[t];
        } else {
            // reference: overlaps.argmax(1) over ALL gt rows, first-max tie-break
            float best = -1.0f;
            asg = 0;
            for (int i = 0; i < n; i++) {
                float4 gi = ((const float4*)gbox)[b * n + i];
                float io = iou_fn(gi, p);
                if (io > best) { best = io; asg = i; }
            }
        }
        float4 g = ((const float4*)gbox)[b * n + asg];
        RowParams rp = row_params(g);
        float iou = iou_fn(g, p);
        float th = fabsf(gang[b * n + asg] - pang[t]);
        float r = ang_measure(rp, th);
        float s = scores[(size_t)t * C + glab[b * n + asg]];
        alv = align_fn(s, iou, r);
        atomicMax(&pam[b * n + asg], ford(alv));
        atomicMax(&pov[b * n + asg], ford(iou));
    }
    assign[t] = asg;
    alignv[t] = alv;
}

__global__ __launch_bounds__(256)
void k3_out(const int* __restrict__ glab, const float* __restrict__ gbox,
            const float* __restrict__ gang, const int* __restrict__ assign,
            const float* __restrict__ alignv, const u32* __restrict__ pam,
            const u32* __restrict__ pov, float* __restrict__ out,
            int bs, int A, int n, int C) {
    __shared__ float s_nv[256];
    __shared__ int s_lf[256];
    int tid = threadIdx.x;
    int base = blockIdx.x * 256;
    int t = base + tid;
    int BA = bs * A;

    if (t < BA) {
        int b = t / A;
        int asg = assign[t];
        bool fg = asg >= 0;
        int tgt = fg ? asg : 0;  // argmax of all-zero column -> row 0
        int lb = glab[b * n + tgt];
        if (lb < 0) lb = 0;

        float* o_tlab = out;
        float* o_tbb = out + BA;
        float* o_tang = out + (size_t)BA * 5;
        float* o_fg = out + (size_t)BA * 6 + (size_t)BA * C;

        o_tlab[t] = (float)lb;
        ((float4*)o_tbb)[t] = ((const float4*)gbox)[b * n + tgt];
        o_tang[t] = gang[b * n + tgt];
        o_fg[t] = fg ? 1.0f : 0.0f;

        float nv = 0.0f;
        if (fg) {
            float pamv = funord(pam[b * n + asg]);
            float povv = funord(pov[b * n + asg]);
            float vv = (alignv[t] * povv) / (pamv + 1e-9f);
            nv = fmaxf(vv, 0.0f);  // 59 other rows contribute exactly 0 to the max
        }
        s_nv[tid] = nv;
        s_lf[tid] = fg ? lb : -1;
    } else {
        s_nv[tid] = 0.0f;
        s_lf[tid] = -1;
    }
    __syncthreads();

    // ts: coalesced float4 writes, (anchor, class-quad) with quad fastest
    int Q = C / 4;  // 20
    int nA = min(256, BA - base);
    if (nA <= 0) return;
    int total = nA * Q;
    float4* o_ts = (float4*)(out + (size_t)BA * 6) + (size_t)base * Q;
    for (int idx = tid; idx < total; idx += 256) {
        int tl = idx / Q;
        int q = idx - tl * Q;
        float nv = s_nv[tl];
        int lf = s_lf[tl];
        int cb = q * 4;
        float4 o;
        o.x = (lf == cb) ? nv : 0.0f;
        o.y = (lf == cb + 1) ? nv : 0.0f;
        o.z = (lf == cb + 2) ? nv : 0.0f;
        o.w = (lf == cb + 3) ? nv : 0.0f;
        o_ts[idx] = o;
    }
}

extern "C" void kernel_launch(void* const* d_in, const int* in_sizes, int n_in,
                              void* d_out, int out_size, void* d_ws, size_t ws_size,
                              hipStream_t stream) {
    const float* scores = (const float*)d_in[0];
    const float* pbox = (const float*)d_in[1];
    const float* pang = (const float*)d_in[2];
    const float* anc = (const float*)d_in[3];
    const int* glab = (const int*)d_in[4];
    const float* gbox = (const float*)d_in[5];
    const float* gang = (const float*)d_in[6];
    const float* mgt = (const float*)d_in[7];

    const int C = 80;
    int A = in_sizes[3] / 2;
    int bs = in_sizes[0] / (A * C);
    int n = in_sizes[4] / bs;
    int BA = bs * A;
    int BN = bs * n;

    char* ws = (char*)d_ws;
    int* cnt = (int*)ws;          ws += sizeof(int) * (size_t)BA;
    int* assign1 = (int*)ws;      ws += sizeof(int) * (size_t)BA;
    int* assign = (int*)ws;       ws += sizeof(int) * (size_t)BA;
    float* alignv = (float*)ws;   ws += sizeof(float) * (size_t)BA;
    u32* pam = (u32*)ws;          ws += sizeof(u32) * (size_t)BN;
    u32* pov = (u32*)ws;          ws += sizeof(u32) * (size_t)BN;
    int* cell_start = (int*)ws;   ws += sizeof(int) * (GC * GC + 1);
    // align to 8 for float2
    ws = (char*)(((size_t)ws + 7) & ~(size_t)7);
    float2* cell_pts = (float2*)ws; ws += sizeof(float2) * (size_t)A;
    u32* cell_idx = (u32*)ws;     ws += sizeof(u32) * (size_t)A;

    k0_init<<<(BA + 255) / 256, 256, 0, stream>>>(cnt, assign1, pam, pov, BA, BN);
    k_grid<<<1, 1024, 0, stream>>>(anc, A, cell_start, cell_pts, cell_idx);
    k1_topk<<<BN, K1_THREADS, 0, stream>>>(scores, pbox, pang, anc, glab, gbox, gang, mgt,
                                           cell_start, cell_pts, cell_idx,
                                           cnt, assign1, bs, A, n, C);
    k2_resolve<<<(BA + 255) / 256, 256, 0, stream>>>(scores, pbox, pang, glab, gbox, gang,
                                                     cnt, assign1, assign, alignv, pam, pov,
                                                     bs, A, n, C);
    k3_out<<<(BA + 255) / 256, 256, 0, stream>>>(glab, gbox, gang, assign, alignv, pam, pov,
                                                 (float*)d_out, bs, A, n, C);
}